// Round 1
// baseline (549.047 us; speedup 1.0000x reference)
//
#include <hip/hip_runtime.h>

#define LEAK 0.01f

__global__ __launch_bounds__(256) void hdrnet_fused(
    const float* __restrict__ grid,   // (N,12,12,16,16)
    const float* __restrict__ full,   // (N,3,H,W)
    const float* __restrict__ w1,     // (3,3,1,1) -> (o,i)
    const float* __restrict__ w3,     // (3,3,3,3) -> (o,i,kh,kw)
    const float* __restrict__ b3,     // (3)
    const float* __restrict__ bias,   // (1)
    float* __restrict__ out)          // (N,3,H,W)
{
    const int H = 1024, W = 1024;
    const int C = 12, D = 12, GH = 16, GW = 16;

    int w = blockIdx.x * blockDim.x + threadIdx.x;
    int h = blockIdx.y * blockDim.y + threadIdx.y;
    int n = blockIdx.z;
    if (w >= W || h >= H) return;

    const float* fn = full + (size_t)n * 3 * H * W;

    // ---- load 3x3 neighborhood for 3 channels (zero-padded SAME) ----
    float v[3][3][3]; // [ch][dy][dx]
    #pragma unroll
    for (int i = 0; i < 3; ++i) {
        const float* fc = fn + (size_t)i * H * W;
        #pragma unroll
        for (int dy = 0; dy < 3; ++dy) {
            int yy = h + dy - 1;
            bool yok = (yy >= 0) && (yy < H);
            #pragma unroll
            for (int dx = 0; dx < 3; ++dx) {
                int xx = w + dx - 1;
                bool ok = yok && (xx >= 0) && (xx < W);
                v[i][dy][dx] = ok ? fc[(size_t)yy * W + xx] : 0.0f;
            }
        }
    }

    // ---- guide: leaky_relu(1x1 conv) + leaky_relu(3x3 conv + b3), mean, +bias, clip ----
    float acc = 0.0f;
    #pragma unroll
    for (int o = 0; o < 3; ++o) {
        float x1 = 0.0f;
        #pragma unroll
        for (int i = 0; i < 3; ++i)
            x1 = fmaf(w1[o * 3 + i], v[i][1][1], x1);
        x1 = (x1 > 0.0f) ? x1 : LEAK * x1;

        float x3 = b3[o];
        #pragma unroll
        for (int i = 0; i < 3; ++i)
            #pragma unroll
            for (int dy = 0; dy < 3; ++dy)
                #pragma unroll
                for (int dx = 0; dx < 3; ++dx)
                    x3 = fmaf(w3[((o * 3 + i) * 3 + dy) * 3 + dx], v[i][dy][dx], x3);
        x3 = (x3 > 0.0f) ? x3 : LEAK * x3;

        acc += x1 + x3;
    }
    float g = acc * (1.0f / 3.0f) + bias[0];
    g = fminf(fmaxf(g, 0.0f), 1.0f);

    // ---- slice coordinates ----
    float fy = ((float)h / (float)(H - 1)) * (float)(GH - 1);
    float fx = ((float)w / (float)(W - 1)) * (float)(GW - 1);
    float fz = g * (float)(D - 1);

    int y0 = (int)floorf(fy); float ty = fy - (float)y0;
    int x0 = (int)floorf(fx); float tx = fx - (float)x0;
    int z0 = (int)floorf(fz); float tz = fz - (float)z0;

    // ---- trilinear slice: 8 corners x 12 channels ----
    const float* gn = grid + (size_t)n * C * D * GH * GW;
    float coeff[12];
    #pragma unroll
    for (int c = 0; c < 12; ++c) coeff[c] = 0.0f;

    #pragma unroll
    for (int dz = 0; dz < 2; ++dz) {
        int zi = min(z0 + dz, D - 1);         // z0 >= 0 since g >= 0
        float wz = dz ? tz : (1.0f - tz);
        #pragma unroll
        for (int dy = 0; dy < 2; ++dy) {
            int yi = min(y0 + dy, GH - 1);
            float wzy = wz * (dy ? ty : (1.0f - ty));
            #pragma unroll
            for (int dx = 0; dx < 2; ++dx) {
                int xi = min(x0 + dx, GW - 1);
                float wt = wzy * (dx ? tx : (1.0f - tx));
                const float* gp = gn + zi * (GH * GW) + yi * GW + xi;
                #pragma unroll
                for (int c = 0; c < 12; ++c)
                    coeff[c] = fmaf(wt, gp[c * (D * GH * GW)], coeff[c]);
            }
        }
    }

    // ---- apply: out[c] = sum_i coeff[4c+i]*full[i] + coeff[4c+3] ----
    float r = v[0][1][1], gg = v[1][1][1], b = v[2][1][1];
    size_t obase = (size_t)n * 3 * H * W + (size_t)h * W + (size_t)w;
    const size_t plane = (size_t)H * W;
    out[obase]             = fmaf(coeff[0], r, fmaf(coeff[1],  gg, fmaf(coeff[2],  b, coeff[3])));
    out[obase + plane]     = fmaf(coeff[4], r, fmaf(coeff[5],  gg, fmaf(coeff[6],  b, coeff[7])));
    out[obase + 2 * plane] = fmaf(coeff[8], r, fmaf(coeff[9],  gg, fmaf(coeff[10], b, coeff[11])));
}

extern "C" void kernel_launch(void* const* d_in, const int* in_sizes, int n_in,
                              void* d_out, int out_size, void* d_ws, size_t ws_size,
                              hipStream_t stream) {
    const float* grid_p = (const float*)d_in[0];
    const float* full_p = (const float*)d_in[1];
    const float* w1_p   = (const float*)d_in[2];
    const float* w3_p   = (const float*)d_in[3];
    const float* b3_p   = (const float*)d_in[4];
    const float* bias_p = (const float*)d_in[5];
    float* out_p = (float*)d_out;

    const int H = 1024, W = 1024, N = 4;
    dim3 block(64, 4, 1);
    dim3 grid_dim(W / 64, H / 4, N);
    hipLaunchKernelGGL(hdrnet_fused, grid_dim, block, 0, stream,
                       grid_p, full_p, w1_p, w3_p, b3_p, bias_p, out_p);
}

// Round 2
// 64.726 us; speedup vs baseline: 8.4826x; 8.4826x over previous
//
#include <hip/hip_runtime.h>

#define LEAK 0.01f

// Problem constants
constexpr int H = 1024, W = 1024, NIMG = 4;
constexpr int GC = 12, GD = 12, GH = 16, GW = 16;

// Tiling: 256 threads (64x4), each thread does 4 pixels along x -> 256x4 tile
constexpr int PX = 4;
constexpr int BX = 64, BY = 4;
constexpr int TILE_W = BX * PX;   // 256
constexpr int XS = 6, YS = 3;     // grid-cell footprint of a tile (see derivation)
constexpr int ROWF = 148;         // padded (z,c) row: 12*12=144 -> 148 floats (bank de-alias)

__global__ __launch_bounds__(256) void hdrnet_fused(
    const float* __restrict__ grid,   // (N,12,12,16,16)
    const float* __restrict__ full,   // (N,3,H,W)
    const float* __restrict__ w1,     // (3,3,1,1)
    const float* __restrict__ w3,     // (3,3,3,3)
    const float* __restrict__ b3,     // (3)
    const float* __restrict__ bias,   // (1)
    float* __restrict__ out)          // (N,3,H,W)
{
    __shared__ float sgrid[YS * XS * ROWF];   // [ly][lx][z*12+c], padded rows

    const int n  = blockIdx.z;
    const int wb = blockIdx.x * TILE_W;
    const int hb = blockIdx.y * BY;

    // ---- stage grid slab into LDS: footprint [ylo..ylo+2] x [xlo..xlo+5], all z, all c ----
    const float scale = 15.0f / 1023.0f;
    const int xlo = (int)(wb * scale);
    const int ylo = (int)(hb * scale);
    const float* gn = grid + (size_t)n * GC * GD * GH * GW;

    const int tid = threadIdx.y * BX + threadIdx.x;
    for (int idx = tid; idx < YS * XS * GD * GC; idx += BX * BY) {
        int lx = idx % XS;
        int t1 = idx / XS;
        int ly = t1 % YS;
        int t2 = t1 / YS;
        int z  = t2 % GD;
        int c  = t2 / GD;
        int xi = min(xlo + lx, GW - 1);
        int yi = min(ylo + ly, GH - 1);
        sgrid[(ly * XS + lx) * ROWF + z * GC + c] =
            gn[((c * GD + z) * GH + yi) * GW + xi];
    }
    __syncthreads();

    const int h  = hb + threadIdx.y;
    const int w0 = wb + threadIdx.x * PX;
    const float* fn = full + (size_t)n * 3 * H * W;

    // ---- weights to registers (wave-uniform -> scalar loads) ----
    float w1c[3][3];
    #pragma unroll
    for (int o = 0; o < 3; ++o)
        #pragma unroll
        for (int i = 0; i < 3; ++i)
            w1c[o][i] = w1[o * 3 + i];
    const float biasv = bias[0];

    // ---- 3x3 conv over 3 ch for 4 pixels, sliding window ----
    float a3[3][PX];
    #pragma unroll
    for (int o = 0; o < 3; ++o) {
        float b = b3[o];
        #pragma unroll
        for (int j = 0; j < PX; ++j) a3[o][j] = b;
    }
    float rgb[3][PX];

    const bool xfast = (w0 >= 4) && (w0 <= W - 12); // covers w0-4 .. w0+7 in-bounds

    #pragma unroll
    for (int i = 0; i < 3; ++i) {
        const float* fc = fn + (size_t)i * H * W;
        #pragma unroll
        for (int dy = 0; dy < 3; ++dy) {
            int yy = h + dy - 1;
            float row[8];   // positions w0-1 .. w0+6
            if (yy >= 0 && yy < H) {
                const float* rp = fc + (size_t)yy * W;
                if (xfast) {
                    const float4* q = (const float4*)(rp + w0 - 4); // 16B aligned
                    float4 v0 = q[0], v1 = q[1], v2 = q[2];
                    row[0] = v0.w;
                    row[1] = v1.x; row[2] = v1.y; row[3] = v1.z; row[4] = v1.w;
                    row[5] = v2.x; row[6] = v2.y; row[7] = v2.z;
                } else {
                    #pragma unroll
                    for (int k = 0; k < 8; ++k) {
                        int xx = w0 - 1 + k;
                        row[k] = (xx >= 0 && xx < W) ? rp[xx] : 0.0f;
                    }
                }
            } else {
                #pragma unroll
                for (int k = 0; k < 8; ++k) row[k] = 0.0f;
            }
            if (dy == 1) {
                #pragma unroll
                for (int j = 0; j < PX; ++j) rgb[i][j] = row[1 + j];
            }
            #pragma unroll
            for (int o = 0; o < 3; ++o) {
                const float k0 = w3[((o * 3 + i) * 3 + dy) * 3 + 0];
                const float k1 = w3[((o * 3 + i) * 3 + dy) * 3 + 1];
                const float k2 = w3[((o * 3 + i) * 3 + dy) * 3 + 2];
                #pragma unroll
                for (int j = 0; j < PX; ++j)
                    a3[o][j] = fmaf(k0, row[j],
                               fmaf(k1, row[j + 1],
                               fmaf(k2, row[j + 2], a3[o][j])));
            }
        }
    }

    // ---- per-thread y slice params (uniform over j) ----
    float fy = (float)h * scale;
    int y0 = (int)fy;
    y0 = min(y0, GH - 2);          // ty=0 edge -> equivalent reformulation
    float ty = fy - (float)y0;
    const int lyr = y0 - ylo;      // 0..1
    const float wy0 = 1.0f - ty, wy1 = ty;

    float4 ov0, ov1, ov2;
    float* ov0p = &ov0.x; float* ov1p = &ov1.x; float* ov2p = &ov2.x;

    #pragma unroll
    for (int j = 0; j < PX; ++j) {
        // guide
        float gacc = 0.0f;
        #pragma unroll
        for (int o = 0; o < 3; ++o) {
            float x1 = fmaf(w1c[o][0], rgb[0][j],
                       fmaf(w1c[o][1], rgb[1][j], w1c[o][2] * rgb[2][j]));
            x1 = (x1 > 0.0f) ? x1 : LEAK * x1;
            float x3 = a3[o][j];
            x3 = (x3 > 0.0f) ? x3 : LEAK * x3;
            gacc += x1 + x3;
        }
        float g = fmaf(gacc, (1.0f / 3.0f), biasv);
        g = fminf(fmaxf(g, 0.0f), 1.0f);

        // slice coords
        float fx = (float)(w0 + j) * scale;
        int x0 = (int)fx;
        x0 = min(x0, GW - 2);
        float tx = fx - (float)x0;
        const int lxr = x0 - xlo;  // 0..4

        float fz = g * 11.0f;
        int z0 = (int)fz;
        z0 = min(z0, GD - 2);
        float tz = fz - (float)z0;
        const float wz0 = 1.0f - tz, wz1 = tz;

        const float* cb = sgrid + (lyr * XS + lxr) * ROWF + z0 * GC;

        float co[12];
        #pragma unroll
        for (int c = 0; c < 12; ++c) co[c] = 0.0f;

        #pragma unroll
        for (int dy = 0; dy < 2; ++dy) {
            const float wyv = dy ? wy1 : wy0;
            #pragma unroll
            for (int dx = 0; dx < 2; ++dx) {
                const float wxy = wyv * (dx ? tx : (1.0f - tx));
                const float wa = wxy * wz0, wb = wxy * wz1;
                const float4* p = (const float4*)(cb + (dy * XS + dx) * ROWF); // 16B aligned
                float4 A0 = p[0], A1 = p[1], A2 = p[2];   // z0 slice, 12 ch
                float4 B0 = p[3], B1 = p[4], B2 = p[5];   // z0+1 slice
                co[0]  = fmaf(wa, A0.x, fmaf(wb, B0.x, co[0]));
                co[1]  = fmaf(wa, A0.y, fmaf(wb, B0.y, co[1]));
                co[2]  = fmaf(wa, A0.z, fmaf(wb, B0.z, co[2]));
                co[3]  = fmaf(wa, A0.w, fmaf(wb, B0.w, co[3]));
                co[4]  = fmaf(wa, A1.x, fmaf(wb, B1.x, co[4]));
                co[5]  = fmaf(wa, A1.y, fmaf(wb, B1.y, co[5]));
                co[6]  = fmaf(wa, A1.z, fmaf(wb, B1.z, co[6]));
                co[7]  = fmaf(wa, A1.w, fmaf(wb, B1.w, co[7]));
                co[8]  = fmaf(wa, A2.x, fmaf(wb, B2.x, co[8]));
                co[9]  = fmaf(wa, A2.y, fmaf(wb, B2.y, co[9]));
                co[10] = fmaf(wa, A2.z, fmaf(wb, B2.z, co[10]));
                co[11] = fmaf(wa, A2.w, fmaf(wb, B2.w, co[11]));
            }
        }

        // apply
        const float r = rgb[0][j], gg = rgb[1][j], b = rgb[2][j];
        ov0p[j] = fmaf(co[0], r, fmaf(co[1],  gg, fmaf(co[2],  b, co[3])));
        ov1p[j] = fmaf(co[4], r, fmaf(co[5],  gg, fmaf(co[6],  b, co[7])));
        ov2p[j] = fmaf(co[8], r, fmaf(co[9],  gg, fmaf(co[10], b, co[11])));
    }

    // ---- coalesced float4 stores, one per channel ----
    const size_t plane = (size_t)H * W;
    float* ob = out + (size_t)n * 3 * plane + (size_t)h * W + w0;
    *(float4*)(ob)             = ov0;
    *(float4*)(ob + plane)     = ov1;
    *(float4*)(ob + 2 * plane) = ov2;
}

extern "C" void kernel_launch(void* const* d_in, const int* in_sizes, int n_in,
                              void* d_out, int out_size, void* d_ws, size_t ws_size,
                              hipStream_t stream) {
    const float* grid_p = (const float*)d_in[0];
    const float* full_p = (const float*)d_in[1];
    const float* w1_p   = (const float*)d_in[2];
    const float* w3_p   = (const float*)d_in[3];
    const float* b3_p   = (const float*)d_in[4];
    const float* bias_p = (const float*)d_in[5];
    float* out_p = (float*)d_out;

    dim3 block(BX, BY, 1);
    dim3 grid_dim(W / TILE_W, H / BY, NIMG);
    hipLaunchKernelGGL(hdrnet_fused, grid_dim, block, 0, stream,
                       grid_p, full_p, w1_p, w3_p, b3_p, bias_p, out_p);
}

// Round 4
// 57.804 us; speedup vs baseline: 9.4984x; 1.1197x over previous
//
#include <hip/hip_runtime.h>

#define LEAK 0.01f

typedef float v2f __attribute__((ext_vector_type(2)));
typedef _Float16 h2 __attribute__((ext_vector_type(2)));

// Problem constants
constexpr int H = 1024, W = 1024, NIMG = 4;
constexpr int GC = 12, GD = 12, GH = 16, GW = 16;
constexpr int NZ = GD - 1;           // 11 z0 values (z-pairs)
constexpr int CELLE = NZ * GC;       // 132 half2 per (y,x) grid cell

// Tiling: 256 threads (64x4), each thread does 4 pixels along x -> 256x4 tile
constexpr int PX = 4;
constexpr int BX = 64, BY = 4;
constexpr int TILE_W = BX * PX;      // 256
constexpr int XS = 6, YS = 3;        // grid-cell footprint of a tile
constexpr int NCELL = XS * YS;       // 18 cells -> LDS 18*132*4B = 9504 B

static __device__ __forceinline__ h2 bch2(float f) {
    return __builtin_bit_cast(h2, f);
}

// cvt_pkrtz returns __fp16x2; bit-cast to our h2 (_Float16x2) — same bits.
static __device__ __forceinline__ h2 pkrtz(float a, float b) {
    return __builtin_bit_cast(h2, __builtin_amdgcn_cvt_pkrtz(a, b));
}

static __device__ __forceinline__ float fdot2f(h2 a, h2 b, float c) {
#if __has_builtin(__builtin_amdgcn_fdot2)
    return __builtin_amdgcn_fdot2(a, b, c, false);
#else
    return (float)a.x * (float)b.x + (float)a.y * (float)b.y + c;
#endif
}

// ---- pre-kernel: build z-pair half2 table in ws ----
// table layout: [n][y*16+x][z0*12+c]  (132 half2 = 528 B contiguous per cell)
__global__ __launch_bounds__(256) void pairgen(const float* __restrict__ grid,
                                               h2* __restrict__ table) {
    const int n  = blockIdx.x / NZ;
    const int z0 = blockIdx.x % NZ;
    const int yx = threadIdx.x;      // 0..255, coalesced over lanes
    const float* src = grid + (size_t)n * GC * GD * GH * GW + yx;
    h2* dst = table + ((size_t)n * 256 + yx) * CELLE + z0 * GC;
    #pragma unroll
    for (int c = 0; c < GC; ++c) {
        float a = src[(c * GD + z0) * 256];
        float b = src[(c * GD + z0 + 1) * 256];
        dst[c] = pkrtz(a, b);
    }
}

__global__ __launch_bounds__(256) void hdrnet_fused(
    const float* __restrict__ grid,   // (N,12,12,16,16)
    const float* __restrict__ full,   // (N,3,H,W)
    const float* __restrict__ w1,     // (3,3,1,1)
    const float* __restrict__ w3,     // (3,3,3,3)
    const float* __restrict__ b3,     // (3)
    const float* __restrict__ bias,   // (1)
    const h2* __restrict__ table,     // pair table or nullptr
    float* __restrict__ out)          // (N,3,H,W)
{
    __shared__ __align__(16) h2 sgrid[NCELL * CELLE];  // [cell][z0*12+c]

    const int n  = blockIdx.z;
    const int wb = blockIdx.x * TILE_W;
    const int hb = blockIdx.y * BY;

    const float scale = 15.0f / 1023.0f;
    const int xlo = (int)(wb * scale);
    const int ylo = (int)(hb * scale);

    const int tid = threadIdx.y * BX + threadIdx.x;

    // ---- stage z-pair slab into LDS ----
    if (table) {
        const float4* tsrc = (const float4*)(table + (size_t)n * 256 * CELLE);
        float4* sdst = (float4*)sgrid;
        for (int e = tid; e < NCELL * CELLE / 4; e += BX * BY) {  // 594 float4
            int cell = e / 33;             // 33 float4 per cell
            int rr   = e - cell * 33;
            int ly = cell / XS, lx = cell - ly * XS;
            int yi = min(ylo + ly, GH - 1);
            int xi = min(xlo + lx, GW - 1);
            sdst[e] = tsrc[(yi * GW + xi) * 33 + rr];
        }
    } else {
        const float* gnn = grid + (size_t)n * GC * GD * GH * GW;
        for (int e = tid; e < NCELL * CELLE; e += BX * BY) {
            int cell = e / CELLE;
            int r    = e - cell * CELLE;
            int z0 = r / GC, c = r - z0 * GC;
            int ly = cell / XS, lx = cell - ly * XS;
            int yi = min(ylo + ly, GH - 1);
            int xi = min(xlo + lx, GW - 1);
            float a = gnn[(c * GD + z0) * 256 + yi * GW + xi];
            float b = gnn[(c * GD + z0 + 1) * 256 + yi * GW + xi];
            sgrid[e] = pkrtz(a, b);
        }
    }
    __syncthreads();

    const int h  = hb + threadIdx.y;
    const int w0 = wb + threadIdx.x * PX;
    const float* fn = full + (size_t)n * 3 * H * W;

    // ---- weights to registers ----
    float w1c[3][3];
    #pragma unroll
    for (int o = 0; o < 3; ++o)
        #pragma unroll
        for (int i = 0; i < 3; ++i)
            w1c[o][i] = w1[o * 3 + i];
    const float biasv = bias[0];

    // ---- 3x3 conv over 3 ch for 4 pixels, packed fp32 (j-pairs) ----
    v2f a3p[3][2];
    #pragma unroll
    for (int o = 0; o < 3; ++o) {
        float b = b3[o];
        a3p[o][0] = (v2f){b, b};
        a3p[o][1] = (v2f){b, b};
    }
    float rgb[3][PX];

    const bool xfast = (w0 >= 4) && (w0 <= W - 12);

    #pragma unroll
    for (int i = 0; i < 3; ++i) {
        const float* fc = fn + (size_t)i * H * W;
        #pragma unroll
        for (int dy = 0; dy < 3; ++dy) {
            int yy = h + dy - 1;
            float row[8];   // positions w0-1 .. w0+6
            if (yy >= 0 && yy < H) {
                const float* rp = fc + (size_t)yy * W;
                if (xfast) {
                    const float4* q = (const float4*)(rp + w0 - 4);
                    float4 v0 = q[0], v1 = q[1], v2 = q[2];
                    row[0] = v0.w;
                    row[1] = v1.x; row[2] = v1.y; row[3] = v1.z; row[4] = v1.w;
                    row[5] = v2.x; row[6] = v2.y; row[7] = v2.z;
                } else {
                    #pragma unroll
                    for (int k = 0; k < 8; ++k) {
                        int xx = w0 - 1 + k;
                        row[k] = (xx >= 0 && xx < W) ? rp[xx] : 0.0f;
                    }
                }
            } else {
                #pragma unroll
                for (int k = 0; k < 8; ++k) row[k] = 0.0f;
            }
            if (dy == 1) {
                #pragma unroll
                for (int j = 0; j < PX; ++j) rgb[i][j] = row[1 + j];
            }
            #pragma unroll
            for (int o = 0; o < 3; ++o) {
                const float* kp = w3 + ((o * 3 + i) * 3 + dy) * 3;
                #pragma unroll
                for (int t = 0; t < 3; ++t) {
                    const float kt = kp[t];
                    v2f kv = (v2f){kt, kt};
                    a3p[o][0] = __builtin_elementwise_fma(
                        kv, (v2f){row[t], row[t + 1]}, a3p[o][0]);
                    a3p[o][1] = __builtin_elementwise_fma(
                        kv, (v2f){row[t + 2], row[t + 3]}, a3p[o][1]);
                }
            }
        }
    }

    // ---- per-thread y slice params ----
    float fy = (float)h * scale;
    int y0 = (int)fy;
    y0 = min(y0, GH - 2);
    float ty = fy - (float)y0;
    const int lyr = y0 - ylo;          // 0..1
    const float wy0 = 1.0f - ty, wy1 = ty;

    float4 ov0, ov1, ov2;
    float* ov0p = &ov0.x; float* ov1p = &ov1.x; float* ov2p = &ov2.x;

    #pragma unroll
    for (int j = 0; j < PX; ++j) {
        // guide
        float gacc = 0.0f;
        #pragma unroll
        for (int o = 0; o < 3; ++o) {
            float x1 = fmaf(w1c[o][0], rgb[0][j],
                       fmaf(w1c[o][1], rgb[1][j], w1c[o][2] * rgb[2][j]));
            x1 = (x1 > 0.0f) ? x1 : LEAK * x1;
            float x3 = a3p[o][j >> 1][j & 1];
            x3 = (x3 > 0.0f) ? x3 : LEAK * x3;
            gacc += x1 + x3;
        }
        float g = fmaf(gacc, (1.0f / 3.0f), biasv);
        g = fminf(fmaxf(g, 0.0f), 1.0f);

        // slice coords
        float fx = (float)(w0 + j) * scale;
        int x0 = (int)fx;
        x0 = min(x0, GW - 2);
        float tx = fx - (float)x0;
        const int lxr = x0 - xlo;      // 0..4

        float fz = g * 11.0f;
        int z0 = (int)fz;
        z0 = min(z0, GD - 2);
        float tz = fz - (float)z0;
        h2 hz = pkrtz(1.0f - tz, tz);
        const int zoff = z0 * GC;

        float co[12];
        #pragma unroll
        for (int c = 0; c < 12; ++c) co[c] = 0.0f;

        #pragma unroll
        for (int dy2 = 0; dy2 < 2; ++dy2) {
            const float wyv = dy2 ? wy1 : wy0;
            const int cy = (lyr + dy2) * XS + lxr;
            #pragma unroll
            for (int dx = 0; dx < 2; ++dx) {
                const float wxy = wyv * (dx ? tx : (1.0f - tx));
                const _Float16 wxyh = (_Float16)wxy;
                h2 wh = hz * (h2){wxyh, wxyh};   // v_pk_mul_f16
                const float4* p = (const float4*)&sgrid[(cy + dx) * CELLE + zoff];
                float4 q0 = p[0], q1 = p[1], q2 = p[2];  // 12 half2 (z-pairs)
                co[0]  = fdot2f(wh, bch2(q0.x), co[0]);
                co[1]  = fdot2f(wh, bch2(q0.y), co[1]);
                co[2]  = fdot2f(wh, bch2(q0.z), co[2]);
                co[3]  = fdot2f(wh, bch2(q0.w), co[3]);
                co[4]  = fdot2f(wh, bch2(q1.x), co[4]);
                co[5]  = fdot2f(wh, bch2(q1.y), co[5]);
                co[6]  = fdot2f(wh, bch2(q1.z), co[6]);
                co[7]  = fdot2f(wh, bch2(q1.w), co[7]);
                co[8]  = fdot2f(wh, bch2(q2.x), co[8]);
                co[9]  = fdot2f(wh, bch2(q2.y), co[9]);
                co[10] = fdot2f(wh, bch2(q2.z), co[10]);
                co[11] = fdot2f(wh, bch2(q2.w), co[11]);
            }
        }

        // apply
        const float r = rgb[0][j], gg = rgb[1][j], b = rgb[2][j];
        ov0p[j] = fmaf(co[0], r, fmaf(co[1],  gg, fmaf(co[2],  b, co[3])));
        ov1p[j] = fmaf(co[4], r, fmaf(co[5],  gg, fmaf(co[6],  b, co[7])));
        ov2p[j] = fmaf(co[8], r, fmaf(co[9],  gg, fmaf(co[10], b, co[11])));
    }

    // ---- coalesced float4 stores ----
    const size_t plane = (size_t)H * W;
    float* ob = out + (size_t)n * 3 * plane + (size_t)h * W + w0;
    *(float4*)(ob)             = ov0;
    *(float4*)(ob + plane)     = ov1;
    *(float4*)(ob + 2 * plane) = ov2;
}

extern "C" void kernel_launch(void* const* d_in, const int* in_sizes, int n_in,
                              void* d_out, int out_size, void* d_ws, size_t ws_size,
                              hipStream_t stream) {
    const float* grid_p = (const float*)d_in[0];
    const float* full_p = (const float*)d_in[1];
    const float* w1_p   = (const float*)d_in[2];
    const float* w3_p   = (const float*)d_in[3];
    const float* b3_p   = (const float*)d_in[4];
    const float* bias_p = (const float*)d_in[5];
    float* out_p = (float*)d_out;

    const size_t tbytes = (size_t)NIMG * 256 * CELLE * sizeof(h2);  // 540,672 B
    h2* table = (d_ws && ws_size >= tbytes) ? (h2*)d_ws : nullptr;

    if (table) {
        hipLaunchKernelGGL(pairgen, dim3(NIMG * NZ), dim3(256), 0, stream,
                           grid_p, table);
    }

    dim3 block(BX, BY, 1);
    dim3 grid_dim(W / TILE_W, H / BY, NIMG);
    hipLaunchKernelGGL(hdrnet_fused, grid_dim, block, 0, stream,
                       grid_p, full_p, w1_p, w3_p, b3_p, bias_p, table, out_p);
}

// Round 5
// 54.664 us; speedup vs baseline: 10.0440x; 1.0574x over previous
//
#include <hip/hip_runtime.h>

#define LEAK 0.01f

typedef float v2f __attribute__((ext_vector_type(2)));
typedef _Float16 h2 __attribute__((ext_vector_type(2)));

// Problem constants
constexpr int H = 1024, W = 1024, NIMG = 4;
constexpr int GC = 12, GD = 12, GH = 16, GW = 16;
constexpr int NZ = GD - 1;           // 11 z0 values (z-pairs)
constexpr int CELLE = NZ * GC;       // 132 half2 per (y,x) grid cell
constexpr int CF4 = 33;              // float4 chunks per cell (132 h2 = 528 B)

// Tiling: 256 threads (64x4), each thread does 4 pixels along x -> 256x4 tile
constexpr int PX = 4;
constexpr int BX = 64, BY = 4;
constexpr int TILE_W = BX * PX;      // 256
constexpr int XS = 6;                // x-cell footprint of a 256-wide tile
// LDS: BY thread-rows, each XS cells of y-LERPED z-pair data: 4*6*132*4B = 12672 B

static __device__ __forceinline__ h2 bch2(float f) {
    return __builtin_bit_cast(h2, f);
}
static __device__ __forceinline__ float bcf(h2 v) {
    return __builtin_bit_cast(float, v);
}
// cvt_pkrtz returns __fp16x2; bit-cast to our h2 (_Float16x2) — same bits.
static __device__ __forceinline__ h2 pkrtz(float a, float b) {
    return __builtin_bit_cast(h2, __builtin_amdgcn_cvt_pkrtz(a, b));
}

static __device__ __forceinline__ float fdot2f(h2 a, h2 b, float c) {
#if __has_builtin(__builtin_amdgcn_fdot2)
    return __builtin_amdgcn_fdot2(a, b, c, false);
#else
    return (float)a.x * (float)b.x + (float)a.y * (float)b.y + c;
#endif
}

// ---- pre-kernel: build z-pair half2 table in ws ----
// table layout: [n][y*16+x][z0*12+c]  (132 half2 = 528 B contiguous per cell)
__global__ __launch_bounds__(256) void pairgen(const float* __restrict__ grid,
                                               h2* __restrict__ table) {
    const int n  = blockIdx.x / NZ;
    const int z0 = blockIdx.x % NZ;
    const int yx = threadIdx.x;      // 0..255, coalesced over lanes
    const float* src = grid + (size_t)n * GC * GD * GH * GW + yx;
    h2* dst = table + ((size_t)n * 256 + yx) * CELLE + z0 * GC;
    #pragma unroll
    for (int c = 0; c < GC; ++c) {
        float a = src[(c * GD + z0) * 256];
        float b = src[(c * GD + z0 + 1) * 256];
        dst[c] = pkrtz(a, b);
    }
}

__global__ __launch_bounds__(256) void hdrnet_fused(
    const float* __restrict__ grid,   // (N,12,12,16,16)
    const float* __restrict__ full,   // (N,3,H,W)
    const float* __restrict__ w1,     // (3,3,1,1)
    const float* __restrict__ w3,     // (3,3,3,3)
    const float* __restrict__ b3,     // (3)
    const float* __restrict__ bias,   // (1)
    const h2* __restrict__ table,     // pair table or nullptr
    float* __restrict__ out)          // (N,3,H,W)
{
    // y-LERPED z-pair slab: [thread-row][x-cell][z0*12+c]
    __shared__ __align__(16) h2 sgrid[BY * XS * CELLE];

    const int n  = blockIdx.z;
    const int wb = blockIdx.x * TILE_W;
    const int hb = blockIdx.y * BY;

    const float scale = 15.0f / 1023.0f;
    const int xlo = (int)(wb * scale);

    const int tid = threadIdx.y * BX + threadIdx.x;

    // ---- stage y-interpolated z-pair slab into LDS ----
    if (table) {
        const float4* tsrc = (const float4*)(table + (size_t)n * 256 * CELLE);
        float4* sdst = (float4*)sgrid;
        for (int e = tid; e < BY * XS * CF4; e += BX * BY) {   // 792 items
            int r  = e / (XS * CF4);
            int t  = e - r * (XS * CF4);
            int lx = t / CF4, q = t - lx * CF4;
            int yy = hb + r;
            float fy = (float)yy * scale;
            int y0 = min((int)fy, GH - 2);
            float ty = fy - (float)y0;
            _Float16 t1 = (_Float16)ty, t0 = (_Float16)(1.0f - ty);
            h2 w0v = (h2){t0, t0}, w1v = (h2){t1, t1};
            int xi = min(xlo + lx, GW - 1);
            const float4* pa = tsrc + (y0 * GW + xi) * CF4 + q;
            const float4* pb = tsrc + ((y0 + 1) * GW + xi) * CF4 + q;
            float4 A = *pa, B = *pb, R;
            R.x = bcf(bch2(A.x) * w0v + bch2(B.x) * w1v);
            R.y = bcf(bch2(A.y) * w0v + bch2(B.y) * w1v);
            R.z = bcf(bch2(A.z) * w0v + bch2(B.z) * w1v);
            R.w = bcf(bch2(A.w) * w0v + bch2(B.w) * w1v);
            sdst[e] = R;
        }
    } else {
        const float* gnn = grid + (size_t)n * GC * GD * GH * GW;
        for (int e = tid; e < BY * XS * CELLE; e += BX * BY) {
            int r  = e / (XS * CELLE);
            int t  = e - r * (XS * CELLE);
            int lx = t / CELLE, u = t - lx * CELLE;
            int z0 = u / GC, c = u - z0 * GC;
            int yy = hb + r;
            float fy = (float)yy * scale;
            int y0 = min((int)fy, GH - 2);
            float ty = fy - (float)y0;
            int xi = min(xlo + lx, GW - 1);
            const float* gp = gnn + ((c * GD + z0) * GH + y0) * GW + xi;
            float a0 = gp[0],  a1 = gp[256];        // z0 / z0+1 at y0
            float b0 = gp[16], b1 = gp[272];        // z0 / z0+1 at y0+1
            sgrid[e] = pkrtz(fmaf(b0 - a0, ty, a0), fmaf(b1 - a1, ty, a1));
        }
    }
    __syncthreads();

    const int h  = hb + threadIdx.y;
    const int w0 = wb + threadIdx.x * PX;
    const float* fn = full + (size_t)n * 3 * H * W;

    // ---- weights to registers ----
    float w1c[3][3];
    #pragma unroll
    for (int o = 0; o < 3; ++o)
        #pragma unroll
        for (int i = 0; i < 3; ++i)
            w1c[o][i] = w1[o * 3 + i];
    const float biasv = bias[0];

    // ---- 3x3 conv over 3 ch for 4 pixels, packed fp32 (j-pairs) ----
    v2f a3p[3][2];
    #pragma unroll
    for (int o = 0; o < 3; ++o) {
        float b = b3[o];
        a3p[o][0] = (v2f){b, b};
        a3p[o][1] = (v2f){b, b};
    }
    float rgb[3][PX];

    const bool xfast = (w0 >= 4) && (w0 <= W - 12);

    #pragma unroll
    for (int i = 0; i < 3; ++i) {
        const float* fc = fn + (size_t)i * H * W;
        #pragma unroll
        for (int dy = 0; dy < 3; ++dy) {
            int yy = h + dy - 1;
            float row[8];   // positions w0-1 .. w0+6
            if (yy >= 0 && yy < H) {
                const float* rp = fc + (size_t)yy * W;
                if (xfast) {
                    const float4* q = (const float4*)(rp + w0 - 4);
                    float4 v0 = q[0], v1 = q[1], v2 = q[2];
                    row[0] = v0.w;
                    row[1] = v1.x; row[2] = v1.y; row[3] = v1.z; row[4] = v1.w;
                    row[5] = v2.x; row[6] = v2.y; row[7] = v2.z;
                } else {
                    #pragma unroll
                    for (int k = 0; k < 8; ++k) {
                        int xx = w0 - 1 + k;
                        row[k] = (xx >= 0 && xx < W) ? rp[xx] : 0.0f;
                    }
                }
            } else {
                #pragma unroll
                for (int k = 0; k < 8; ++k) row[k] = 0.0f;
            }
            if (dy == 1) {
                #pragma unroll
                for (int j = 0; j < PX; ++j) rgb[i][j] = row[1 + j];
            }
            #pragma unroll
            for (int o = 0; o < 3; ++o) {
                const float* kp = w3 + ((o * 3 + i) * 3 + dy) * 3;
                #pragma unroll
                for (int t = 0; t < 3; ++t) {
                    const float kt = kp[t];
                    v2f kv = (v2f){kt, kt};
                    a3p[o][0] = __builtin_elementwise_fma(
                        kv, (v2f){row[t], row[t + 1]}, a3p[o][0]);
                    a3p[o][1] = __builtin_elementwise_fma(
                        kv, (v2f){row[t + 2], row[t + 3]}, a3p[o][1]);
                }
            }
        }
    }

    const int srow = threadIdx.y * XS;       // this thread-row's cell base
    const float4* sg4 = (const float4*)sgrid;

    float4 ov0, ov1, ov2;
    float* ov0p = &ov0.x; float* ov1p = &ov1.x; float* ov2p = &ov2.x;

    #pragma unroll
    for (int j = 0; j < PX; ++j) {
        // guide
        float gacc = 0.0f;
        #pragma unroll
        for (int o = 0; o < 3; ++o) {
            float x1 = fmaf(w1c[o][0], rgb[0][j],
                       fmaf(w1c[o][1], rgb[1][j], w1c[o][2] * rgb[2][j]));
            x1 = (x1 > 0.0f) ? x1 : LEAK * x1;
            float x3 = a3p[o][j >> 1][j & 1];
            x3 = (x3 > 0.0f) ? x3 : LEAK * x3;
            gacc += x1 + x3;
        }
        float g = fmaf(gacc, (1.0f / 3.0f), biasv);
        g = fminf(fmaxf(g, 0.0f), 1.0f);

        // slice coords (y already folded into LDS)
        float fx = (float)(w0 + j) * scale;
        int x0 = (int)fx;
        x0 = min(x0, GW - 2);
        float tx = fx - (float)x0;
        const int lxr = x0 - xlo;      // 0..4

        float fz = g * 11.0f;
        int z0 = (int)fz;
        z0 = min(z0, GD - 2);
        float tz = fz - (float)z0;
        h2 hz = pkrtz(1.0f - tz, tz);
        _Float16 hx0 = (_Float16)(1.0f - tx), hx1 = (_Float16)tx;
        h2 wA = hz * (h2){hx0, hx0};   // v_pk_mul_f16
        h2 wB = hz * (h2){hx1, hx1};

        const float4* pA = sg4 + (srow + lxr) * CF4 + z0 * 3;
        const float4* pB = pA + CF4;
        float4 A0 = pA[0], A1 = pA[1], A2 = pA[2];
        float4 B0 = pB[0], B1 = pB[1], B2 = pB[2];

        float co[12];
        co[0]  = fdot2f(wA, bch2(A0.x), fdot2f(wB, bch2(B0.x), 0.0f));
        co[1]  = fdot2f(wA, bch2(A0.y), fdot2f(wB, bch2(B0.y), 0.0f));
        co[2]  = fdot2f(wA, bch2(A0.z), fdot2f(wB, bch2(B0.z), 0.0f));
        co[3]  = fdot2f(wA, bch2(A0.w), fdot2f(wB, bch2(B0.w), 0.0f));
        co[4]  = fdot2f(wA, bch2(A1.x), fdot2f(wB, bch2(B1.x), 0.0f));
        co[5]  = fdot2f(wA, bch2(A1.y), fdot2f(wB, bch2(B1.y), 0.0f));
        co[6]  = fdot2f(wA, bch2(A1.z), fdot2f(wB, bch2(B1.z), 0.0f));
        co[7]  = fdot2f(wA, bch2(A1.w), fdot2f(wB, bch2(B1.w), 0.0f));
        co[8]  = fdot2f(wA, bch2(A2.x), fdot2f(wB, bch2(B2.x), 0.0f));
        co[9]  = fdot2f(wA, bch2(A2.y), fdot2f(wB, bch2(B2.y), 0.0f));
        co[10] = fdot2f(wA, bch2(A2.z), fdot2f(wB, bch2(B2.z), 0.0f));
        co[11] = fdot2f(wA, bch2(A2.w), fdot2f(wB, bch2(B2.w), 0.0f));

        // apply
        const float r = rgb[0][j], gg = rgb[1][j], b = rgb[2][j];
        ov0p[j] = fmaf(co[0], r, fmaf(co[1],  gg, fmaf(co[2],  b, co[3])));
        ov1p[j] = fmaf(co[4], r, fmaf(co[5],  gg, fmaf(co[6],  b, co[7])));
        ov2p[j] = fmaf(co[8], r, fmaf(co[9],  gg, fmaf(co[10], b, co[11])));
    }

    // ---- coalesced float4 stores ----
    const size_t plane = (size_t)H * W;
    float* ob = out + (size_t)n * 3 * plane + (size_t)h * W + w0;
    *(float4*)(ob)             = ov0;
    *(float4*)(ob + plane)     = ov1;
    *(float4*)(ob + 2 * plane) = ov2;
}

extern "C" void kernel_launch(void* const* d_in, const int* in_sizes, int n_in,
                              void* d_out, int out_size, void* d_ws, size_t ws_size,
                              hipStream_t stream) {
    const float* grid_p = (const float*)d_in[0];
    const float* full_p = (const float*)d_in[1];
    const float* w1_p   = (const float*)d_in[2];
    const float* w3_p   = (const float*)d_in[3];
    const float* b3_p   = (const float*)d_in[4];
    const float* bias_p = (const float*)d_in[5];
    float* out_p = (float*)d_out;

    const size_t tbytes = (size_t)NIMG * 256 * CELLE * sizeof(h2);  // 540,672 B
    h2* table = (d_ws && ws_size >= tbytes) ? (h2*)d_ws : nullptr;

    if (table) {
        hipLaunchKernelGGL(pairgen, dim3(NIMG * NZ), dim3(256), 0, stream,
                           grid_p, table);
    }

    dim3 block(BX, BY, 1);
    dim3 grid_dim(W / TILE_W, H / BY, NIMG);
    hipLaunchKernelGGL(hdrnet_fused, grid_dim, block, 0, stream,
                       grid_p, full_p, w1_p, w3_p, b3_p, bias_p, table, out_p);
}

// Round 6
// 52.907 us; speedup vs baseline: 10.3776x; 1.0332x over previous
//
#include <hip/hip_runtime.h>

#define LEAK 0.01f

typedef float v2f __attribute__((ext_vector_type(2)));
typedef _Float16 h2 __attribute__((ext_vector_type(2)));

// Problem constants
constexpr int H = 1024, W = 1024, NIMG = 4;
constexpr int GC = 12, GD = 12, GH = 16, GW = 16;
constexpr int NZ = GD - 1;           // 11 z0 values (z-pairs)
constexpr int CELLE = NZ * GC;       // 132 half2 per (y,x) grid cell
constexpr int CF4 = 33;              // float4 chunks per cell (132 h2 = 528 B)

// Tiling: 256 threads (64x4), each thread does 8 pixels along x -> 512x4 tile
constexpr int PX = 8;
constexpr int BX = 64, BY = 4;
constexpr int TILE_W = BX * PX;      // 512
constexpr int XS = 10;               // x-cell footprint of a 512-wide tile
// LDS: BY thread-rows, each XS cells of y-LERPED z-pair data: 4*10*132*4B = 21120 B

static __device__ __forceinline__ h2 bch2(float f) {
    return __builtin_bit_cast(h2, f);
}
static __device__ __forceinline__ float bcf(h2 v) {
    return __builtin_bit_cast(float, v);
}
// cvt_pkrtz returns __fp16x2; bit-cast to our h2 (_Float16x2) — same bits.
static __device__ __forceinline__ h2 pkrtz(float a, float b) {
    return __builtin_bit_cast(h2, __builtin_amdgcn_cvt_pkrtz(a, b));
}

static __device__ __forceinline__ float fdot2f(h2 a, h2 b, float c) {
#if __has_builtin(__builtin_amdgcn_fdot2)
    return __builtin_amdgcn_fdot2(a, b, c, false);
#else
    return (float)a.x * (float)b.x + (float)a.y * (float)b.y + c;
#endif
}

// packed leaky-relu: max(x,0) + LEAK*min(x,0)
static __device__ __forceinline__ v2f lrelu2(v2f x) {
    v2f z = (v2f){0.0f, 0.0f};
    v2f mx = __builtin_elementwise_max(x, z);
    v2f mn = __builtin_elementwise_min(x, z);
    return __builtin_elementwise_fma((v2f){LEAK, LEAK}, mn, mx);
}

// ---- pre-kernel: build z-pair half2 table in ws ----
// table layout: [n][y*16+x][z0*12+c]  (132 half2 = 528 B contiguous per cell)
__global__ __launch_bounds__(256) void pairgen(const float* __restrict__ grid,
                                               h2* __restrict__ table) {
    const int n  = blockIdx.x / NZ;
    const int z0 = blockIdx.x % NZ;
    const int yx = threadIdx.x;      // 0..255, coalesced over lanes
    const float* src = grid + (size_t)n * GC * GD * GH * GW + yx;
    h2* dst = table + ((size_t)n * 256 + yx) * CELLE + z0 * GC;
    #pragma unroll
    for (int c = 0; c < GC; ++c) {
        float a = src[(c * GD + z0) * 256];
        float b = src[(c * GD + z0 + 1) * 256];
        dst[c] = pkrtz(a, b);
    }
}

__global__ __launch_bounds__(256) void hdrnet_fused(
    const float* __restrict__ grid,   // (N,12,12,16,16)
    const float* __restrict__ full,   // (N,3,H,W)
    const float* __restrict__ w1,     // (3,3,1,1)
    const float* __restrict__ w3,     // (3,3,3,3)
    const float* __restrict__ b3,     // (3)
    const float* __restrict__ bias,   // (1)
    const h2* __restrict__ table,     // pair table or nullptr
    float* __restrict__ out)          // (N,3,H,W)
{
    // y-LERPED z-pair slab: [thread-row][x-cell][z0*12+c]
    __shared__ __align__(16) h2 sgrid[BY * XS * CELLE];

    const int n  = blockIdx.z;
    const int wb = blockIdx.x * TILE_W;
    const int hb = blockIdx.y * BY;

    const float scale = 15.0f / 1023.0f;
    const int xlo = (int)(wb * scale);

    const int tid = threadIdx.y * BX + threadIdx.x;

    // ---- stage y-interpolated z-pair slab into LDS ----
    if (table) {
        const float4* tsrc = (const float4*)(table + (size_t)n * 256 * CELLE);
        float4* sdst = (float4*)sgrid;
        for (int e = tid; e < BY * XS * CF4; e += BX * BY) {   // 1320 items
            int r  = e / (XS * CF4);
            int t  = e - r * (XS * CF4);
            int lx = t / CF4, q = t - lx * CF4;
            int yy = hb + r;
            float fy = (float)yy * scale;
            int y0 = min((int)fy, GH - 2);
            float ty = fy - (float)y0;
            _Float16 t1 = (_Float16)ty, t0 = (_Float16)(1.0f - ty);
            h2 w0v = (h2){t0, t0}, w1v = (h2){t1, t1};
            int xi = min(xlo + lx, GW - 1);
            const float4* pa = tsrc + (y0 * GW + xi) * CF4 + q;
            const float4* pb = tsrc + ((y0 + 1) * GW + xi) * CF4 + q;
            float4 A = *pa, B = *pb, R;
            R.x = bcf(bch2(A.x) * w0v + bch2(B.x) * w1v);
            R.y = bcf(bch2(A.y) * w0v + bch2(B.y) * w1v);
            R.z = bcf(bch2(A.z) * w0v + bch2(B.z) * w1v);
            R.w = bcf(bch2(A.w) * w0v + bch2(B.w) * w1v);
            sdst[e] = R;
        }
    } else {
        const float* gnn = grid + (size_t)n * GC * GD * GH * GW;
        for (int e = tid; e < BY * XS * CELLE; e += BX * BY) {
            int r  = e / (XS * CELLE);
            int t  = e - r * (XS * CELLE);
            int lx = t / CELLE, u = t - lx * CELLE;
            int z0 = u / GC, c = u - z0 * GC;
            int yy = hb + r;
            float fy = (float)yy * scale;
            int y0 = min((int)fy, GH - 2);
            float ty = fy - (float)y0;
            int xi = min(xlo + lx, GW - 1);
            const float* gp = gnn + ((c * GD + z0) * GH + y0) * GW + xi;
            float a0 = gp[0],  a1 = gp[256];        // z0 / z0+1 at y0
            float b0 = gp[16], b1 = gp[272];        // z0 / z0+1 at y0+1
            sgrid[e] = pkrtz(fmaf(b0 - a0, ty, a0), fmaf(b1 - a1, ty, a1));
        }
    }
    __syncthreads();

    const int h  = hb + threadIdx.y;
    const int w0 = wb + threadIdx.x * PX;
    const float* fn = full + (size_t)n * 3 * H * W;

    // ---- weights to registers ----
    float w1c[3][3];
    #pragma unroll
    for (int o = 0; o < 3; ++o)
        #pragma unroll
        for (int i = 0; i < 3; ++i)
            w1c[o][i] = w1[o * 3 + i];
    const float biasv = bias[0];

    // ---- 3x3 conv over 3 ch for 8 pixels, packed fp32 j-pairs ----
    // a3p[o][p]: conv acc for pixel pair p (j=2p,2p+1)
    v2f a3p[3][4];
    #pragma unroll
    for (int o = 0; o < 3; ++o) {
        float b = b3[o];
        #pragma unroll
        for (int p = 0; p < 4; ++p) a3p[o][p] = (v2f){b, b};
    }
    // rgbp[i][p]: center pixels (for guide x1 and apply)
    v2f rgbp[3][4];

    const bool xfast = (w0 >= 8) && (w0 <= W - 16);

    #pragma unroll
    for (int i = 0; i < 3; ++i) {
        const float* fc = fn + (size_t)i * H * W;
        #pragma unroll
        for (int dy = 0; dy < 3; ++dy) {
            int yy = h + dy - 1;
            // row positions w0-1 .. w0+8, held as 5 aligned pairs row2[k] = {row[2k],row[2k+1]}
            v2f row2[5];
            if (yy >= 0 && yy < H) {
                const float* rp = fc + (size_t)yy * W;
                if (xfast) {
                    float lm = rp[w0 - 1];
                    float4 a = *(const float4*)(rp + w0);       // w0..w0+3
                    float4 b = *(const float4*)(rp + w0 + 4);   // w0+4..w0+7
                    float rm = rp[w0 + 8];
                    row2[0] = (v2f){lm, a.x};
                    row2[1] = (v2f){a.y, a.z};
                    row2[2] = (v2f){a.w, b.x};
                    row2[3] = (v2f){b.y, b.z};
                    row2[4] = (v2f){b.w, rm};
                } else {
                    float rowv[10];
                    #pragma unroll
                    for (int k = 0; k < 10; ++k) {
                        int xx = w0 - 1 + k;
                        rowv[k] = (xx >= 0 && xx < W) ? rp[xx] : 0.0f;
                    }
                    #pragma unroll
                    for (int k = 0; k < 5; ++k)
                        row2[k] = (v2f){rowv[2 * k], rowv[2 * k + 1]};
                }
            } else {
                #pragma unroll
                for (int k = 0; k < 5; ++k) row2[k] = (v2f){0.0f, 0.0f};
            }
            // odd-shifted pairs rv1[p] = {row[2p+1], row[2p+2]}
            v2f rv1[4];
            #pragma unroll
            for (int p = 0; p < 4; ++p)
                rv1[p] = (v2f){row2[p].y, row2[p + 1].x};
            if (dy == 1) {
                #pragma unroll
                for (int p = 0; p < 4; ++p) rgbp[i][p] = rv1[p];  // centers = row[1+2p], row[2+2p]
            }
            #pragma unroll
            for (int o = 0; o < 3; ++o) {
                const float* kp = w3 + ((o * 3 + i) * 3 + dy) * 3;
                const float k0 = kp[0], k1 = kp[1], k2 = kp[2];
                v2f kv0 = (v2f){k0, k0}, kv1 = (v2f){k1, k1}, kv2 = (v2f){k2, k2};
                #pragma unroll
                for (int p = 0; p < 4; ++p) {
                    // taps for pair p: row[2p..2p+1] (=row2[p]), row[2p+1..2p+2] (=rv1[p]), row[2p+2..2p+3] (=row2[p+1])
                    a3p[o][p] = __builtin_elementwise_fma(kv0, row2[p],     a3p[o][p]);
                    a3p[o][p] = __builtin_elementwise_fma(kv1, rv1[p],      a3p[o][p]);
                    a3p[o][p] = __builtin_elementwise_fma(kv2, row2[p + 1], a3p[o][p]);
                }
            }
        }
    }

    // ---- packed guide: gaccp[p] over pixel pairs ----
    v2f gaccp[4];
    #pragma unroll
    for (int p = 0; p < 4; ++p) {
        v2f acc = (v2f){0.0f, 0.0f};
        #pragma unroll
        for (int o = 0; o < 3; ++o) {
            v2f x1 = __builtin_elementwise_fma((v2f){w1c[o][0], w1c[o][0]}, rgbp[0][p],
                     __builtin_elementwise_fma((v2f){w1c[o][1], w1c[o][1]}, rgbp[1][p],
                                               (v2f){w1c[o][2], w1c[o][2]} * rgbp[2][p]));
            acc = acc + lrelu2(x1) + lrelu2(a3p[o][p]);
        }
        gaccp[p] = __builtin_elementwise_fma(acc, (v2f){1.0f/3.0f, 1.0f/3.0f},
                                             (v2f){biasv, biasv});
    }

    const int srow = threadIdx.y * XS;       // this thread-row's cell base
    const float4* sg4 = (const float4*)sgrid;

    float4 ov[3][2];

    #pragma unroll
    for (int j = 0; j < PX; ++j) {
        float g = gaccp[j >> 1][j & 1];
        g = fminf(fmaxf(g, 0.0f), 1.0f);

        // slice coords (y already folded into LDS)
        float fx = (float)(w0 + j) * scale;
        int x0 = (int)fx;
        x0 = min(x0, GW - 2);
        float tx = fx - (float)x0;
        const int lxr = x0 - xlo;      // 0..8

        float fz = g * 11.0f;
        int z0 = (int)fz;
        z0 = min(z0, GD - 2);
        float tz = fz - (float)z0;
        h2 hz = pkrtz(1.0f - tz, tz);
        _Float16 hx0 = (_Float16)(1.0f - tx), hx1 = (_Float16)tx;
        h2 wA = hz * (h2){hx0, hx0};   // v_pk_mul_f16
        h2 wB = hz * (h2){hx1, hx1};

        const float4* pA = sg4 + (srow + lxr) * CF4 + z0 * 3;
        const float4* pB = pA + CF4;
        float4 A0 = pA[0], A1 = pA[1], A2 = pA[2];
        float4 B0 = pB[0], B1 = pB[1], B2 = pB[2];

        float co[12];
        co[0]  = fdot2f(wA, bch2(A0.x), fdot2f(wB, bch2(B0.x), 0.0f));
        co[1]  = fdot2f(wA, bch2(A0.y), fdot2f(wB, bch2(B0.y), 0.0f));
        co[2]  = fdot2f(wA, bch2(A0.z), fdot2f(wB, bch2(B0.z), 0.0f));
        co[3]  = fdot2f(wA, bch2(A0.w), fdot2f(wB, bch2(B0.w), 0.0f));
        co[4]  = fdot2f(wA, bch2(A1.x), fdot2f(wB, bch2(B1.x), 0.0f));
        co[5]  = fdot2f(wA, bch2(A1.y), fdot2f(wB, bch2(B1.y), 0.0f));
        co[6]  = fdot2f(wA, bch2(A1.z), fdot2f(wB, bch2(B1.z), 0.0f));
        co[7]  = fdot2f(wA, bch2(A1.w), fdot2f(wB, bch2(B1.w), 0.0f));
        co[8]  = fdot2f(wA, bch2(A2.x), fdot2f(wB, bch2(B2.x), 0.0f));
        co[9]  = fdot2f(wA, bch2(A2.y), fdot2f(wB, bch2(B2.y), 0.0f));
        co[10] = fdot2f(wA, bch2(A2.z), fdot2f(wB, bch2(B2.z), 0.0f));
        co[11] = fdot2f(wA, bch2(A2.w), fdot2f(wB, bch2(B2.w), 0.0f));

        // apply
        const float r  = rgbp[0][j >> 1][j & 1];
        const float gg = rgbp[1][j >> 1][j & 1];
        const float b  = rgbp[2][j >> 1][j & 1];
        float* o0 = (float*)&ov[0][j >> 2];
        float* o1 = (float*)&ov[1][j >> 2];
        float* o2 = (float*)&ov[2][j >> 2];
        o0[j & 3] = fmaf(co[0], r, fmaf(co[1],  gg, fmaf(co[2],  b, co[3])));
        o1[j & 3] = fmaf(co[4], r, fmaf(co[5],  gg, fmaf(co[6],  b, co[7])));
        o2[j & 3] = fmaf(co[8], r, fmaf(co[9],  gg, fmaf(co[10], b, co[11])));
    }

    // ---- coalesced float4 stores, two per channel ----
    const size_t plane = (size_t)H * W;
    float* ob = out + (size_t)n * 3 * plane + (size_t)h * W + w0;
    #pragma unroll
    for (int ch = 0; ch < 3; ++ch) {
        *(float4*)(ob + ch * plane)     = ov[ch][0];
        *(float4*)(ob + ch * plane + 4) = ov[ch][1];
    }
}

extern "C" void kernel_launch(void* const* d_in, const int* in_sizes, int n_in,
                              void* d_out, int out_size, void* d_ws, size_t ws_size,
                              hipStream_t stream) {
    const float* grid_p = (const float*)d_in[0];
    const float* full_p = (const float*)d_in[1];
    const float* w1_p   = (const float*)d_in[2];
    const float* w3_p   = (const float*)d_in[3];
    const float* b3_p   = (const float*)d_in[4];
    const float* bias_p = (const float*)d_in[5];
    float* out_p = (float*)d_out;

    const size_t tbytes = (size_t)NIMG * 256 * CELLE * sizeof(h2);  // 540,672 B
    h2* table = (d_ws && ws_size >= tbytes) ? (h2*)d_ws : nullptr;

    if (table) {
        hipLaunchKernelGGL(pairgen, dim3(NIMG * NZ), dim3(256), 0, stream,
                           grid_p, table);
    }

    dim3 block(BX, BY, 1);
    dim3 grid_dim(W / TILE_W, H / BY, NIMG);
    hipLaunchKernelGGL(hdrnet_fused, grid_dim, block, 0, stream,
                       grid_p, full_p, w1_p, w3_p, b3_p, bias_p, table, out_p);
}